// Round 16
// baseline (303.247 us; speedup 1.0000x reference)
//
#include <hip/hip_runtime.h>

typedef unsigned short u16;
typedef unsigned int   u32;
typedef short bf16x8 __attribute__((ext_vector_type(8)));
typedef float f32x2  __attribute__((ext_vector_type(2)));
typedef float f32x4  __attribute__((ext_vector_type(4)));
typedef float f32x16 __attribute__((ext_vector_type(16)));

#define NB  32
#define NQ  1024
#define GS  1024
#define NH  8
#define SCQ (0.25f * 1.4426950408889634f)   /* 1/sqrt(16) * log2(e) */
#define MBIG (-1.0e30f)

#define MFMA16(a, b, c) __builtin_amdgcn_mfma_f32_16x16x32_bf16(a, b, c, 0, 0, 0)
#define MFMA32(a, b, c) __builtin_amdgcn_mfma_f32_32x32x16_bf16(a, b, c, 0, 0, 0)

__device__ __forceinline__ u16 f2bf(float f) {  // RNE float->bf16 bits
    u32 u = __float_as_uint(f);
    return (u16)((u + 0x7fffu + ((u >> 16) & 1u)) >> 16);
}
// packed round-half-up: result = bf(a) | bf(b)<<16, 3 VALU ops via v_perm_b32
__device__ __forceinline__ u32 pk2bf(float a, float b) {
    u32 ua = __float_as_uint(a) + 0x8000u;
    u32 ub = __float_as_uint(b) + 0x8000u;
    return __builtin_amdgcn_perm(ub, ua, 0x07060302u);  // bytes [b3 b2 a3 a2]
}

// ---------------------------------------------------------------------------
// MFMA GEMM v14 (best measured): C[128x128] = A[128x128] * W^T, K=128.
// A-fragment global loads issued FIRST; W-stage emits one ds_write_b128 per
// thread-iter; epilogue via LDS aliasing Ws. One tile per block (v15's KV
// fusion serialized passes and regressed — proj is latency-bound; block
// parallelism wins over traffic reduction).
// MODE 0: bf16 out row-major.
// MODE 2: bf16 out transposed per batch with sigma slot permutation
//         (swap quads 1<->2) so flash's in-register P feeds PV directly.
// ---------------------------------------------------------------------------
template <int MODE>
__device__ __forceinline__ void mgemm(const float* __restrict__ Ain,
                                      const float* __restrict__ Wraw,
                                      float wsc,
                                      u16* __restrict__ outb,
                                      u16* Ws, int row0) {
    const int t    = threadIdx.x;
    const int wv   = t >> 6;
    const int lane = t & 63;
    const int quad = lane >> 4;
    const int c    = lane & 15;

    // ---- A fragments FIRST: rows wv*32+c and wv*32+16+c, k-octet kt*32+quad*8
    const float* a0p = &Ain[(size_t)(row0 + wv * 32 + c) * 128];
    const float* a1p = &Ain[(size_t)(row0 + wv * 32 + 16 + c) * 128];
    bf16x8 af0[4], af1[4];
#pragma unroll
    for (int kt = 0; kt < 4; ++kt) {
        int k0 = kt * 32 + quad * 8;
        float4 x0 = *(const float4*)&a0p[k0];
        float4 x1 = *(const float4*)&a0p[k0 + 4];
        float4 y0 = *(const float4*)&a1p[k0];
        float4 y1 = *(const float4*)&a1p[k0 + 4];
        int4 p0, p1;
        p0.x = (int)pk2bf(x0.x, x0.y);  p0.y = (int)pk2bf(x0.z, x0.w);
        p0.z = (int)pk2bf(x1.x, x1.y);  p0.w = (int)pk2bf(x1.z, x1.w);
        p1.x = (int)pk2bf(y0.x, y0.y);  p1.y = (int)pk2bf(y0.z, y0.w);
        p1.z = (int)pk2bf(y1.x, y1.y);  p1.w = (int)pk2bf(y1.z, y1.w);
        __builtin_memcpy(&af0[kt], &p0, 16);
        __builtin_memcpy(&af1[kt], &p1, 16);
    }

    // ---- W stage: Ws[col*136 + k] = f2bf(W[h][k][e]*wsc), col = 16h+e.
#pragma unroll
    for (int g0 = 0; g0 < 2048; g0 += 256) {
        int idx = g0 + t;
        int col = idx & 127;
        int k0  = (idx >> 7) * 8;
        const float* wsrc = &Wraw[(col >> 4) * 2048 + (col & 15)];
        float w0 = wsrc[(k0 + 0) * 16], w1 = wsrc[(k0 + 1) * 16];
        float w2 = wsrc[(k0 + 2) * 16], w3 = wsrc[(k0 + 3) * 16];
        float w4 = wsrc[(k0 + 4) * 16], w5 = wsrc[(k0 + 5) * 16];
        float w6 = wsrc[(k0 + 6) * 16], w7 = wsrc[(k0 + 7) * 16];
        int4 pk;
        pk.x = (int)((u32)f2bf(w0 * wsc) | ((u32)f2bf(w1 * wsc) << 16));
        pk.y = (int)((u32)f2bf(w2 * wsc) | ((u32)f2bf(w3 * wsc) << 16));
        pk.z = (int)((u32)f2bf(w4 * wsc) | ((u32)f2bf(w5 * wsc) << 16));
        pk.w = (int)((u32)f2bf(w6 * wsc) | ((u32)f2bf(w7 * wsc) << 16));
        *(int4*)&Ws[col * 136 + k0] = pk;
    }
    __syncthreads();                     // Ws ready

    const f32x4 zf = {0.f, 0.f, 0.f, 0.f};
    f32x4 acc[2][8];
#pragma unroll
    for (int s = 0; s < 2; ++s)
#pragma unroll
        for (int j = 0; j < 8; ++j) acc[s][j] = zf;

#pragma unroll
    for (int kt = 0; kt < 4; ++kt) {
#pragma unroll
        for (int j = 0; j < 8; ++j) {
            bf16x8 bfr = *(const bf16x8*)&Ws[(j * 16 + c) * 136 + kt * 32 + quad * 8];
            acc[0][j] = MFMA16(af0[kt], bfr, acc[0][j]);
            acc[1][j] = MFMA16(af1[kt], bfr, acc[1][j]);
        }
    }

    // ---- epilogue via LDS (aliases Ws): scatter bf16, coalesced int4 out ----
    __syncthreads();                     // all Ws reads complete
    u16* Os = Ws;
#pragma unroll
    for (int s = 0; s < 2; ++s)
#pragma unroll
        for (int j = 0; j < 8; ++j)
#pragma unroll
            for (int r = 0; r < 4; ++r) {
                int lrow = wv * 32 + s * 16 + quad * 4 + r;
                int col  = j * 16 + c;
                u16 v = f2bf(acc[s][j][r]);
                if (MODE == 0) {
                    Os[lrow * 136 + col] = v;
                } else {
                    int u   = lrow & 15;
                    int sw  = ((u >> 2) ^ (u >> 3)) & 1;     // sigma: swap quads 1<->2
                    int tbp = lrow ^ (sw ? 12 : 0);
                    Os[col * 136 + tbp] = v;
                }
            }
    __syncthreads();

    if (MODE == 0) {
#pragma unroll
        for (int it = 0; it < 8; ++it) {
            int chunk = it * 256 + t;
            int lrow = chunk >> 4, c0 = (chunk & 15) * 8;
            *(int4*)&outb[(size_t)(row0 + lrow) * 128 + c0] =
                *(const int4*)&Os[lrow * 136 + c0];
        }
    } else {
        int bI = row0 >> 10, tb0 = row0 & 1023;
#pragma unroll
        for (int it = 0; it < 8; ++it) {
            int chunk = it * 256 + t;
            int col = chunk >> 4, t0 = (chunk & 15) * 8;
            *(int4*)&outb[(size_t)bI * (128 * 1024) + (size_t)col * 1024 + tb0 + t0] =
                *(const int4*)&Os[col * 136 + t0];
        }
    }
}

__global__ __launch_bounds__(256, 3) void proj_mfma(const float* __restrict__ q,
                                                    const float* __restrict__ h,
                                                    const float* __restrict__ Wq,
                                                    const float* __restrict__ Wk,
                                                    const float* __restrict__ Wv,
                                                    const float* __restrict__ Wout,
                                                    u16* __restrict__ Qb,
                                                    u16* __restrict__ Kb,
                                                    u16* __restrict__ Vtg,
                                                    u16* __restrict__ Wob) {
    __shared__ u16 Ws[128 * 136];
    int y = blockIdx.y;
    if (y == 3) {
        // Wob prep: [d][he] = Wout[he>>4][he&15][d], blocks x<64
        if (blockIdx.x < 64) {
            int i = blockIdx.x * 256 + threadIdx.x;    // 0..16383
            int d = i >> 7, he = i & 127;
            Wob[i] = f2bf(Wout[(he >> 4) * 2048 + (he & 15) * 128 + d]);
        }
        return;
    }
    int row0 = blockIdx.x * 128;
    if (y == 0)      mgemm<0>(q, Wq, SCQ,  Qb,  Ws, row0);
    else if (y == 1) mgemm<0>(h, Wk, 1.0f, Kb,  Ws, row0);
    else             mgemm<2>(h, Wv, 1.0f, Vtg, Ws, row0);
}

// ---------------------------------------------------------------------------
// MFMA flash attention + fused out-projection, v16 = v9 (PROVEN: 94-96 us,
// reproduced rounds 9/12/14/15) + s_setprio(1) around the MFMA clusters
// (catalog T5: +4-7% when waves have role diversity — our 8 waves free-run
// between barriers interleaving staging/exp/MFMA; 3 unsynced blocks/CU).
// Zero register cost, zero layout change, zero numerics change.
// v8/v10/v11/v13/v15 all refuted: any added per-thread state crosses the
// 128-VGPR (512,4) cliff and scratches. ~60 live VGPR here.
// LDS: 17408 (Kt, rows 0..31 reused as Hs) + 18432 (Vtt) + 8704 (Mf)
//    = 44544 B -> 3 blocks/CU.
// ---------------------------------------------------------------------------
__global__ __launch_bounds__(512, 4) void flash_mfma(const u16* __restrict__ Qb,
                                                     const u16* __restrict__ Kb,
                                                     const u16* __restrict__ Vtg,
                                                     const int* __restrict__ mask,
                                                     const u16* __restrict__ Wob,
                                                     float* __restrict__ out) {
    __shared__ u16 Kt[64 * 136];        // [key][dim]; rows 0..31 reused as Hs
    __shared__ u16 Vtt[128 * 72];       // [dim][slot], sigma-permuted slots
    __shared__ float Mf[32 * 68];       // mask addend [q][key 0..63]

    const int b    = blockIdx.x;
    const int q0   = blockIdx.y * 32;
    const int t    = threadIdx.x;
    const int hh   = t >> 6;
    const int lane = t & 63;
    const int quad = lane >> 4;         // 0..3
    const int c    = lane & 15;
    const int qq   = lane & 31;         // score col (q-row) / A-frag row (key)
    const int hi   = lane >> 5;         // k-slice select for 32x32x16 frags

    // Q fragment (B operand of swapped score MFMA): full 16-dim head slice
    bf16x8 qf = *(const bf16x8*)&Qb[((size_t)b * NQ + q0 + qq) * 128 +
                                    hh * 16 + hi * 8];

    f32x16 O32;
#pragma unroll
    for (int r = 0; r < 16; ++r) O32[r] = 0.f;
    float lsum = 0.f;

    // staging indices
    const int skey = t >> 4;            // K: key 0..31 (+32), dim octet (t&15)*8
    const int sd0  = (t & 15) * 8;
    const int vdim = t >> 2;            // V: dim 0..127, slot octet (t&3)*8 (+32)
    const int vs0  = (t & 3) * 8;
    const int mrow = t >> 4;            // M: q-row 0..31, key pair (t&15)*2 (+32)
    const int mk0  = (t & 15) * 2;

    const u16* Kptr = &Kb[((size_t)b * GS + skey) * 128 + sd0];
    const u16* Vptr = &Vtg[(size_t)b * (128 * 1024) + (size_t)vdim * 1024 + vs0];
    const int* Mptr = &mask[((size_t)b * NQ + q0 + mrow) * GS + mk0];

    int4 kreg0 = *(const int4*)Kptr;
    int4 kreg1 = *(const int4*)(Kptr + 32 * 128);
    int4 vreg0 = *(const int4*)Vptr;
    int4 vreg1 = *(const int4*)(Vptr + 32);
    int2 mreg0 = *(const int2*)Mptr;
    int2 mreg1 = *(const int2*)(Mptr + 32);

    for (int g0 = 0; g0 < GS; g0 += 64) {
        __syncthreads();
        *(int4*)&Kt[skey * 136 + sd0]        = kreg0;
        *(int4*)&Kt[(32 + skey) * 136 + sd0] = kreg1;
        *(int4*)&Vtt[vdim * 72 + vs0]        = vreg0;
        *(int4*)&Vtt[vdim * 72 + 32 + vs0]   = vreg1;
        f32x2 mm0, mm1;
        mm0.x = mreg0.x ? MBIG : 0.f;
        mm0.y = mreg0.y ? MBIG : 0.f;
        mm1.x = mreg1.x ? MBIG : 0.f;
        mm1.y = mreg1.y ? MBIG : 0.f;
        *(f32x2*)&Mf[mrow * 68 + mk0]      = mm0;
        *(f32x2*)&Mf[mrow * 68 + 32 + mk0] = mm1;
        __syncthreads();

        if (g0 + 64 < GS) {
            Kptr += 64 * 128;
            kreg0 = *(const int4*)Kptr;
            kreg1 = *(const int4*)(Kptr + 32 * 128);
            Vptr += 64;
            vreg0 = *(const int4*)Vptr;
            vreg1 = *(const int4*)(Vptr + 32);
            Mptr += 64;
            mreg0 = *(const int2*)Mptr;
            mreg1 = *(const int2*)(Mptr + 32);
        }

        // two independent swapped-score chains: D[key][q], K=16 head dim
        bf16x8 kf0 = *(const bf16x8*)&Kt[qq * 136 + hh * 16 + hi * 8];
        bf16x8 kf1 = *(const bf16x8*)&Kt[(32 + qq) * 136 + hh * 16 + hi * 8];
        f32x16 c0, c1;
#pragma unroll
        for (int blk = 0; blk < 4; ++blk) {
            f32x4 m0 = *(const f32x4*)&Mf[qq * 68 + 8 * blk + 4 * hi];
            f32x4 m1 = *(const f32x4*)&Mf[qq * 68 + 32 + 8 * blk + 4 * hi];
            c0[4 * blk + 0] = m0.x;  c0[4 * blk + 1] = m0.y;
            c0[4 * blk + 2] = m0.z;  c0[4 * blk + 3] = m0.w;
            c1[4 * blk + 0] = m1.x;  c1[4 * blk + 1] = m1.y;
            c1[4 * blk + 2] = m1.z;  c1[4 * blk + 3] = m1.w;
        }
        __builtin_amdgcn_s_setprio(1);
        f32x16 s0 = MFMA32(kf0, qf, c0);
        f32x16 s1 = MFMA32(kf1, qf, c1);
        __builtin_amdgcn_s_setprio(0);

        bf16x8 vf0 = *(const bf16x8*)&Vtt[(hh * 16 + c) * 72 + hi * 8];
        bf16x8 vf1 = *(const bf16x8*)&Vtt[(hh * 16 + c) * 72 + 16 + hi * 8];
        bf16x8 vf2 = *(const bf16x8*)&Vtt[(hh * 16 + c) * 72 + 32 + hi * 8];
        bf16x8 vf3 = *(const bf16x8*)&Vtt[(hh * 16 + c) * 72 + 48 + hi * 8];

        // chunk 0: exp -> lsum -> pack -> PV (keys 0..31), all in-register
#pragma unroll
        for (int r = 0; r < 16; ++r) s0[r] = __builtin_amdgcn_exp2f(s0[r]);
        lsum += ((s0[0] + s0[1]) + (s0[2] + s0[3])) + ((s0[4] + s0[5]) + (s0[6] + s0[7])) +
                (((s0[8] + s0[9]) + (s0[10] + s0[11])) + ((s0[12] + s0[13]) + (s0[14] + s0[15])));
        {
            int4 pa, pb;
            pa.x = (int)pk2bf(s0[0],  s0[1]);  pa.y = (int)pk2bf(s0[2],  s0[3]);
            pa.z = (int)pk2bf(s0[4],  s0[5]);  pa.w = (int)pk2bf(s0[6],  s0[7]);
            pb.x = (int)pk2bf(s0[8],  s0[9]);  pb.y = (int)pk2bf(s0[10], s0[11]);
            pb.z = (int)pk2bf(s0[12], s0[13]); pb.w = (int)pk2bf(s0[14], s0[15]);
            bf16x8 p0, p1;
            __builtin_memcpy(&p0, &pa, 16);
            __builtin_memcpy(&p1, &pb, 16);
            __builtin_amdgcn_s_setprio(1);
            O32 = MFMA32(vf0, p0, O32);
            O32 = MFMA32(vf1, p1, O32);
            __builtin_amdgcn_s_setprio(0);
        }

        // chunk 1: keys 32..63
#pragma unroll
        for (int r = 0; r < 16; ++r) s1[r] = __builtin_amdgcn_exp2f(s1[r]);
        lsum += ((s1[0] + s1[1]) + (s1[2] + s1[3])) + ((s1[4] + s1[5]) + (s1[6] + s1[7])) +
                (((s1[8] + s1[9]) + (s1[10] + s1[11])) + ((s1[12] + s1[13]) + (s1[14] + s1[15])));
        {
            int4 pa, pb;
            pa.x = (int)pk2bf(s1[0],  s1[1]);  pa.y = (int)pk2bf(s1[2],  s1[3]);
            pa.z = (int)pk2bf(s1[4],  s1[5]);  pa.w = (int)pk2bf(s1[6],  s1[7]);
            pb.x = (int)pk2bf(s1[8],  s1[9]);  pb.y = (int)pk2bf(s1[10], s1[11]);
            pb.z = (int)pk2bf(s1[12], s1[13]); pb.w = (int)pk2bf(s1[14], s1[15]);
            bf16x8 p2, p3;
            __builtin_memcpy(&p2, &pa, 16);
            __builtin_memcpy(&p3, &pb, 16);
            __builtin_amdgcn_s_setprio(1);
            O32 = MFMA32(vf2, p2, O32);
            O32 = MFMA32(vf3, p3, O32);
            __builtin_amdgcn_s_setprio(0);
        }
    }

    // per-lane q-row denominator: combine hi halves
    lsum += __shfl_xor(lsum, 32);
    float rl = (lsum > 0.f) ? 1.f / lsum : 0.f;

    // O32 reg r (r<8) holds O^T[dim][q=qq]: dims r<4: 4hi+r ; r>=4: 8+4hi+(r-4)
    u32 h0 = pk2bf(O32[0] * rl, O32[1] * rl);
    u32 h1 = pk2bf(O32[2] * rl, O32[3] * rl);
    u32 h2 = pk2bf(O32[4] * rl, O32[5] * rl);
    u32 h3 = pk2bf(O32[6] * rl, O32[7] * rl);
    __syncthreads();                    // all Kt/Vtt reads done (Hs aliases Kt)
    u16* Hs = Kt;
    int2 ha; ha.x = (int)h0; ha.y = (int)h1;
    int2 hb; hb.x = (int)h2; hb.y = (int)h3;
    *(int2*)&Hs[qq * 136 + hh * 16 + 4 * hi]     = ha;
    *(int2*)&Hs[qq * 136 + hh * 16 + 8 + 4 * hi] = hb;
    __syncthreads();

    // fused out-projection: wave hh computes out cols hh*16..+15
    const f32x4 zf = {0.f, 0.f, 0.f, 0.f};
    f32x4 oacc[2] = {zf, zf};
#pragma unroll
    for (int kt = 0; kt < 4; ++kt) {
        bf16x8 bfr = *(const bf16x8*)&Wob[(hh * 16 + c) * 128 + kt * 32 + quad * 8];
#pragma unroll
        for (int s = 0; s < 2; ++s) {
            bf16x8 af = *(const bf16x8*)&Hs[(s * 16 + c) * 136 + kt * 32 + quad * 8];
            oacc[s] = MFMA16(af, bfr, oacc[s]);
        }
    }
#pragma unroll
    for (int s = 0; s < 2; ++s)
#pragma unroll
        for (int r = 0; r < 4; ++r)
            out[((size_t)b * NQ + q0 + s * 16 + quad * 4 + r) * 128 + hh * 16 + c] =
                oacc[s][r];
}

extern "C" void kernel_launch(void* const* d_in, const int* in_sizes, int n_in,
                              void* d_out, int out_size, void* d_ws, size_t ws_size,
                              hipStream_t stream) {
    const float* q    = (const float*)d_in[0];
    const float* h    = (const float*)d_in[1];
    const int*   mask = (const int*)d_in[2];
    const float* Wq   = (const float*)d_in[3];
    const float* Wk   = (const float*)d_in[4];
    const float* Wv   = (const float*)d_in[5];
    const float* Wout = (const float*)d_in[6];
    float* out = (float*)d_out;

    const size_t NTOK = (size_t)NB * NQ;     // 32768
    u16* Qb  = (u16*)d_ws;                   // 8 MB each
    u16* Kb  = Qb + NTOK * 128;
    u16* Vtg = Kb + NTOK * 128;              // V^T per batch, sigma-permuted slots
    u16* Wob = Vtg + NTOK * 128;             // prepped Wout, 32 KB

    proj_mfma<<<dim3(256, 4), 256, 0, stream>>>(q, h, Wq, Wk, Wv, Wout,
                                                Qb, Kb, Vtg, Wob);
    flash_mfma<<<dim3(NB, NQ / 32), 512, 0, stream>>>(Qb, Kb, Vtg, mask,
                                                      Wob, out);
}

// Round 17
// 274.061 us; speedup vs baseline: 1.1065x; 1.1065x over previous
//
#include <hip/hip_runtime.h>

typedef unsigned short u16;
typedef unsigned int   u32;
typedef short bf16x8 __attribute__((ext_vector_type(8)));
typedef float f32x2  __attribute__((ext_vector_type(2)));
typedef float f32x4  __attribute__((ext_vector_type(4)));
typedef float f32x16 __attribute__((ext_vector_type(16)));

#define NB  32
#define NQ  1024
#define GS  1024
#define NH  8
#define SCQ (0.25f * 1.4426950408889634f)   /* 1/sqrt(16) * log2(e) */
#define MBIG (-1.0e30f)

#define MFMA16(a, b, c) __builtin_amdgcn_mfma_f32_16x16x32_bf16(a, b, c, 0, 0, 0)
#define MFMA32(a, b, c) __builtin_amdgcn_mfma_f32_32x32x16_bf16(a, b, c, 0, 0, 0)

__device__ __forceinline__ u16 f2bf(float f) {  // RNE float->bf16 bits
    u32 u = __float_as_uint(f);
    return (u16)((u + 0x7fffu + ((u >> 16) & 1u)) >> 16);
}
// packed round-half-up: result = bf(a) | bf(b)<<16, 3 VALU ops via v_perm_b32
__device__ __forceinline__ u32 pk2bf(float a, float b) {
    u32 ua = __float_as_uint(a) + 0x8000u;
    u32 ub = __float_as_uint(b) + 0x8000u;
    return __builtin_amdgcn_perm(ub, ua, 0x07060302u);  // bytes [b3 b2 a3 a2]
}

// ---------------------------------------------------------------------------
// MFMA GEMM v14 (best measured): C[128x128] = A[128x128] * W^T, K=128.
// A-fragment global loads issued FIRST; W-stage emits one ds_write_b128 per
// thread-iter; epilogue via LDS aliasing Ws. One tile per block (v15's KV
// fusion serialized passes and regressed — proj is latency-bound; block
// parallelism wins over traffic reduction).
// MODE 0: bf16 out row-major.
// MODE 2: bf16 out transposed per batch with sigma slot permutation
//         (swap quads 1<->2) so flash's in-register P feeds PV directly.
// ---------------------------------------------------------------------------
template <int MODE>
__device__ __forceinline__ void mgemm(const float* __restrict__ Ain,
                                      const float* __restrict__ Wraw,
                                      float wsc,
                                      u16* __restrict__ outb,
                                      u16* Ws, int row0) {
    const int t    = threadIdx.x;
    const int wv   = t >> 6;
    const int lane = t & 63;
    const int quad = lane >> 4;
    const int c    = lane & 15;

    // ---- A fragments FIRST: rows wv*32+c and wv*32+16+c, k-octet kt*32+quad*8
    const float* a0p = &Ain[(size_t)(row0 + wv * 32 + c) * 128];
    const float* a1p = &Ain[(size_t)(row0 + wv * 32 + 16 + c) * 128];
    bf16x8 af0[4], af1[4];
#pragma unroll
    for (int kt = 0; kt < 4; ++kt) {
        int k0 = kt * 32 + quad * 8;
        float4 x0 = *(const float4*)&a0p[k0];
        float4 x1 = *(const float4*)&a0p[k0 + 4];
        float4 y0 = *(const float4*)&a1p[k0];
        float4 y1 = *(const float4*)&a1p[k0 + 4];
        int4 p0, p1;
        p0.x = (int)pk2bf(x0.x, x0.y);  p0.y = (int)pk2bf(x0.z, x0.w);
        p0.z = (int)pk2bf(x1.x, x1.y);  p0.w = (int)pk2bf(x1.z, x1.w);
        p1.x = (int)pk2bf(y0.x, y0.y);  p1.y = (int)pk2bf(y0.z, y0.w);
        p1.z = (int)pk2bf(y1.x, y1.y);  p1.w = (int)pk2bf(y1.z, y1.w);
        __builtin_memcpy(&af0[kt], &p0, 16);
        __builtin_memcpy(&af1[kt], &p1, 16);
    }

    // ---- W stage: Ws[col*136 + k] = f2bf(W[h][k][e]*wsc), col = 16h+e.
#pragma unroll
    for (int g0 = 0; g0 < 2048; g0 += 256) {
        int idx = g0 + t;
        int col = idx & 127;
        int k0  = (idx >> 7) * 8;
        const float* wsrc = &Wraw[(col >> 4) * 2048 + (col & 15)];
        float w0 = wsrc[(k0 + 0) * 16], w1 = wsrc[(k0 + 1) * 16];
        float w2 = wsrc[(k0 + 2) * 16], w3 = wsrc[(k0 + 3) * 16];
        float w4 = wsrc[(k0 + 4) * 16], w5 = wsrc[(k0 + 5) * 16];
        float w6 = wsrc[(k0 + 6) * 16], w7 = wsrc[(k0 + 7) * 16];
        int4 pk;
        pk.x = (int)((u32)f2bf(w0 * wsc) | ((u32)f2bf(w1 * wsc) << 16));
        pk.y = (int)((u32)f2bf(w2 * wsc) | ((u32)f2bf(w3 * wsc) << 16));
        pk.z = (int)((u32)f2bf(w4 * wsc) | ((u32)f2bf(w5 * wsc) << 16));
        pk.w = (int)((u32)f2bf(w6 * wsc) | ((u32)f2bf(w7 * wsc) << 16));
        *(int4*)&Ws[col * 136 + k0] = pk;
    }
    __syncthreads();                     // Ws ready

    const f32x4 zf = {0.f, 0.f, 0.f, 0.f};
    f32x4 acc[2][8];
#pragma unroll
    for (int s = 0; s < 2; ++s)
#pragma unroll
        for (int j = 0; j < 8; ++j) acc[s][j] = zf;

#pragma unroll
    for (int kt = 0; kt < 4; ++kt) {
#pragma unroll
        for (int j = 0; j < 8; ++j) {
            bf16x8 bfr = *(const bf16x8*)&Ws[(j * 16 + c) * 136 + kt * 32 + quad * 8];
            acc[0][j] = MFMA16(af0[kt], bfr, acc[0][j]);
            acc[1][j] = MFMA16(af1[kt], bfr, acc[1][j]);
        }
    }

    // ---- epilogue via LDS (aliases Ws): scatter bf16, coalesced int4 out ----
    __syncthreads();                     // all Ws reads complete
    u16* Os = Ws;
#pragma unroll
    for (int s = 0; s < 2; ++s)
#pragma unroll
        for (int j = 0; j < 8; ++j)
#pragma unroll
            for (int r = 0; r < 4; ++r) {
                int lrow = wv * 32 + s * 16 + quad * 4 + r;
                int col  = j * 16 + c;
                u16 v = f2bf(acc[s][j][r]);
                if (MODE == 0) {
                    Os[lrow * 136 + col] = v;
                } else {
                    int u   = lrow & 15;
                    int sw  = ((u >> 2) ^ (u >> 3)) & 1;     // sigma: swap quads 1<->2
                    int tbp = lrow ^ (sw ? 12 : 0);
                    Os[col * 136 + tbp] = v;
                }
            }
    __syncthreads();

    if (MODE == 0) {
#pragma unroll
        for (int it = 0; it < 8; ++it) {
            int chunk = it * 256 + t;
            int lrow = chunk >> 4, c0 = (chunk & 15) * 8;
            *(int4*)&outb[(size_t)(row0 + lrow) * 128 + c0] =
                *(const int4*)&Os[lrow * 136 + c0];
        }
    } else {
        int bI = row0 >> 10, tb0 = row0 & 1023;
#pragma unroll
        for (int it = 0; it < 8; ++it) {
            int chunk = it * 256 + t;
            int col = chunk >> 4, t0 = (chunk & 15) * 8;
            *(int4*)&outb[(size_t)bI * (128 * 1024) + (size_t)col * 1024 + tb0 + t0] =
                *(const int4*)&Os[col * 136 + t0];
        }
    }
}

__global__ __launch_bounds__(256, 3) void proj_mfma(const float* __restrict__ q,
                                                    const float* __restrict__ h,
                                                    const float* __restrict__ Wq,
                                                    const float* __restrict__ Wk,
                                                    const float* __restrict__ Wv,
                                                    const float* __restrict__ Wout,
                                                    u16* __restrict__ Qb,
                                                    u16* __restrict__ Kb,
                                                    u16* __restrict__ Vtg,
                                                    u16* __restrict__ Wob) {
    __shared__ u16 Ws[128 * 136];
    int y = blockIdx.y;
    if (y == 3) {
        // Wob prep: [d][he] = Wout[he>>4][he&15][d], blocks x<64
        if (blockIdx.x < 64) {
            int i = blockIdx.x * 256 + threadIdx.x;    // 0..16383
            int d = i >> 7, he = i & 127;
            Wob[i] = f2bf(Wout[(he >> 4) * 2048 + (he & 15) * 128 + d]);
        }
        return;
    }
    int row0 = blockIdx.x * 128;
    if (y == 0)      mgemm<0>(q, Wq, SCQ,  Qb,  Ws, row0);
    else if (y == 1) mgemm<0>(h, Wk, 1.0f, Kb,  Ws, row0);
    else             mgemm<2>(h, Wv, 1.0f, Vtg, Ws, row0);
}

// ---------------------------------------------------------------------------
// MFMA flash attention + fused out-projection, v9 (PROVEN: flash 94-96 us,
// reproduced rounds 9/12/14/15). v4 score path (Mf FLOAT mask staging;
// C-operand build is pure LDS reads) + in-register PV (pack->MFMA32 with
// sigma-permuted V; no Ps LDS). KVBLK=64, double-barrier staging, 1-tile
// prefetch. ~60 live VGPR at (512,4). Refuted levers: v8 bit-mask VALU
// (+26%), v10 QBLK-by-state (spill), v11 dbuf-unroll (spill), v13
// QBLK-by-waves (64-VGPR cap spill), v15 KV-fusion (parallelism loss),
// v16 setprio (codegen perturbation -> partial spill). This is the
// practical plateau at this occupancy/register envelope.
// LDS: 17408 (Kt, rows 0..31 reused as Hs) + 18432 (Vtt) + 8704 (Mf)
//    = 44544 B -> 3 blocks/CU.
// ---------------------------------------------------------------------------
__global__ __launch_bounds__(512, 4) void flash_mfma(const u16* __restrict__ Qb,
                                                     const u16* __restrict__ Kb,
                                                     const u16* __restrict__ Vtg,
                                                     const int* __restrict__ mask,
                                                     const u16* __restrict__ Wob,
                                                     float* __restrict__ out) {
    __shared__ u16 Kt[64 * 136];        // [key][dim]; rows 0..31 reused as Hs
    __shared__ u16 Vtt[128 * 72];       // [dim][slot], sigma-permuted slots
    __shared__ float Mf[32 * 68];       // mask addend [q][key 0..63]

    const int b    = blockIdx.x;
    const int q0   = blockIdx.y * 32;
    const int t    = threadIdx.x;
    const int hh   = t >> 6;
    const int lane = t & 63;
    const int quad = lane >> 4;         // 0..3
    const int c    = lane & 15;
    const int qq   = lane & 31;         // score col (q-row) / A-frag row (key)
    const int hi   = lane >> 5;         // k-slice select for 32x32x16 frags

    // Q fragment (B operand of swapped score MFMA): full 16-dim head slice
    bf16x8 qf = *(const bf16x8*)&Qb[((size_t)b * NQ + q0 + qq) * 128 +
                                    hh * 16 + hi * 8];

    f32x16 O32;
#pragma unroll
    for (int r = 0; r < 16; ++r) O32[r] = 0.f;
    float lsum = 0.f;

    // staging indices
    const int skey = t >> 4;            // K: key 0..31 (+32), dim octet (t&15)*8
    const int sd0  = (t & 15) * 8;
    const int vdim = t >> 2;            // V: dim 0..127, slot octet (t&3)*8 (+32)
    const int vs0  = (t & 3) * 8;
    const int mrow = t >> 4;            // M: q-row 0..31, key pair (t&15)*2 (+32)
    const int mk0  = (t & 15) * 2;

    const u16* Kptr = &Kb[((size_t)b * GS + skey) * 128 + sd0];
    const u16* Vptr = &Vtg[(size_t)b * (128 * 1024) + (size_t)vdim * 1024 + vs0];
    const int* Mptr = &mask[((size_t)b * NQ + q0 + mrow) * GS + mk0];

    int4 kreg0 = *(const int4*)Kptr;
    int4 kreg1 = *(const int4*)(Kptr + 32 * 128);
    int4 vreg0 = *(const int4*)Vptr;
    int4 vreg1 = *(const int4*)(Vptr + 32);
    int2 mreg0 = *(const int2*)Mptr;
    int2 mreg1 = *(const int2*)(Mptr + 32);

    for (int g0 = 0; g0 < GS; g0 += 64) {
        __syncthreads();
        *(int4*)&Kt[skey * 136 + sd0]        = kreg0;
        *(int4*)&Kt[(32 + skey) * 136 + sd0] = kreg1;
        *(int4*)&Vtt[vdim * 72 + vs0]        = vreg0;
        *(int4*)&Vtt[vdim * 72 + 32 + vs0]   = vreg1;
        f32x2 mm0, mm1;
        mm0.x = mreg0.x ? MBIG : 0.f;
        mm0.y = mreg0.y ? MBIG : 0.f;
        mm1.x = mreg1.x ? MBIG : 0.f;
        mm1.y = mreg1.y ? MBIG : 0.f;
        *(f32x2*)&Mf[mrow * 68 + mk0]      = mm0;
        *(f32x2*)&Mf[mrow * 68 + 32 + mk0] = mm1;
        __syncthreads();

        if (g0 + 64 < GS) {
            Kptr += 64 * 128;
            kreg0 = *(const int4*)Kptr;
            kreg1 = *(const int4*)(Kptr + 32 * 128);
            Vptr += 64;
            vreg0 = *(const int4*)Vptr;
            vreg1 = *(const int4*)(Vptr + 32);
            Mptr += 64;
            mreg0 = *(const int2*)Mptr;
            mreg1 = *(const int2*)(Mptr + 32);
        }

        // two independent swapped-score chains: D[key][q], K=16 head dim
        bf16x8 kf0 = *(const bf16x8*)&Kt[qq * 136 + hh * 16 + hi * 8];
        bf16x8 kf1 = *(const bf16x8*)&Kt[(32 + qq) * 136 + hh * 16 + hi * 8];
        f32x16 c0, c1;
#pragma unroll
        for (int blk = 0; blk < 4; ++blk) {
            f32x4 m0 = *(const f32x4*)&Mf[qq * 68 + 8 * blk + 4 * hi];
            f32x4 m1 = *(const f32x4*)&Mf[qq * 68 + 32 + 8 * blk + 4 * hi];
            c0[4 * blk + 0] = m0.x;  c0[4 * blk + 1] = m0.y;
            c0[4 * blk + 2] = m0.z;  c0[4 * blk + 3] = m0.w;
            c1[4 * blk + 0] = m1.x;  c1[4 * blk + 1] = m1.y;
            c1[4 * blk + 2] = m1.z;  c1[4 * blk + 3] = m1.w;
        }
        f32x16 s0 = MFMA32(kf0, qf, c0);
        f32x16 s1 = MFMA32(kf1, qf, c1);

        bf16x8 vf0 = *(const bf16x8*)&Vtt[(hh * 16 + c) * 72 + hi * 8];
        bf16x8 vf1 = *(const bf16x8*)&Vtt[(hh * 16 + c) * 72 + 16 + hi * 8];
        bf16x8 vf2 = *(const bf16x8*)&Vtt[(hh * 16 + c) * 72 + 32 + hi * 8];
        bf16x8 vf3 = *(const bf16x8*)&Vtt[(hh * 16 + c) * 72 + 48 + hi * 8];

        // chunk 0: exp -> lsum -> pack -> PV (keys 0..31), all in-register
#pragma unroll
        for (int r = 0; r < 16; ++r) s0[r] = __builtin_amdgcn_exp2f(s0[r]);
        lsum += ((s0[0] + s0[1]) + (s0[2] + s0[3])) + ((s0[4] + s0[5]) + (s0[6] + s0[7])) +
                (((s0[8] + s0[9]) + (s0[10] + s0[11])) + ((s0[12] + s0[13]) + (s0[14] + s0[15])));
        {
            int4 pa, pb;
            pa.x = (int)pk2bf(s0[0],  s0[1]);  pa.y = (int)pk2bf(s0[2],  s0[3]);
            pa.z = (int)pk2bf(s0[4],  s0[5]);  pa.w = (int)pk2bf(s0[6],  s0[7]);
            pb.x = (int)pk2bf(s0[8],  s0[9]);  pb.y = (int)pk2bf(s0[10], s0[11]);
            pb.z = (int)pk2bf(s0[12], s0[13]); pb.w = (int)pk2bf(s0[14], s0[15]);
            bf16x8 p0, p1;
            __builtin_memcpy(&p0, &pa, 16);
            __builtin_memcpy(&p1, &pb, 16);
            O32 = MFMA32(vf0, p0, O32);
            O32 = MFMA32(vf1, p1, O32);
        }

        // chunk 1: keys 32..63
#pragma unroll
        for (int r = 0; r < 16; ++r) s1[r] = __builtin_amdgcn_exp2f(s1[r]);
        lsum += ((s1[0] + s1[1]) + (s1[2] + s1[3])) + ((s1[4] + s1[5]) + (s1[6] + s1[7])) +
                (((s1[8] + s1[9]) + (s1[10] + s1[11])) + ((s1[12] + s1[13]) + (s1[14] + s1[15])));
        {
            int4 pa, pb;
            pa.x = (int)pk2bf(s1[0],  s1[1]);  pa.y = (int)pk2bf(s1[2],  s1[3]);
            pa.z = (int)pk2bf(s1[4],  s1[5]);  pa.w = (int)pk2bf(s1[6],  s1[7]);
            pb.x = (int)pk2bf(s1[8],  s1[9]);  pb.y = (int)pk2bf(s1[10], s1[11]);
            pb.z = (int)pk2bf(s1[12], s1[13]); pb.w = (int)pk2bf(s1[14], s1[15]);
            bf16x8 p2, p3;
            __builtin_memcpy(&p2, &pa, 16);
            __builtin_memcpy(&p3, &pb, 16);
            O32 = MFMA32(vf2, p2, O32);
            O32 = MFMA32(vf3, p3, O32);
        }
    }

    // per-lane q-row denominator: combine hi halves
    lsum += __shfl_xor(lsum, 32);
    float rl = (lsum > 0.f) ? 1.f / lsum : 0.f;

    // O32 reg r (r<8) holds O^T[dim][q=qq]: dims r<4: 4hi+r ; r>=4: 8+4hi+(r-4)
    u32 h0 = pk2bf(O32[0] * rl, O32[1] * rl);
    u32 h1 = pk2bf(O32[2] * rl, O32[3] * rl);
    u32 h2 = pk2bf(O32[4] * rl, O32[5] * rl);
    u32 h3 = pk2bf(O32[6] * rl, O32[7] * rl);
    __syncthreads();                    // all Kt/Vtt reads done (Hs aliases Kt)
    u16* Hs = Kt;
    int2 ha; ha.x = (int)h0; ha.y = (int)h1;
    int2 hb; hb.x = (int)h2; hb.y = (int)h3;
    *(int2*)&Hs[qq * 136 + hh * 16 + 4 * hi]     = ha;
    *(int2*)&Hs[qq * 136 + hh * 16 + 8 + 4 * hi] = hb;
    __syncthreads();

    // fused out-projection: wave hh computes out cols hh*16..+15
    const f32x4 zf = {0.f, 0.f, 0.f, 0.f};
    f32x4 oacc[2] = {zf, zf};
#pragma unroll
    for (int kt = 0; kt < 4; ++kt) {
        bf16x8 bfr = *(const bf16x8*)&Wob[(hh * 16 + c) * 128 + kt * 32 + quad * 8];
#pragma unroll
        for (int s = 0; s < 2; ++s) {
            bf16x8 af = *(const bf16x8*)&Hs[(s * 16 + c) * 136 + kt * 32 + quad * 8];
            oacc[s] = MFMA16(af, bfr, oacc[s]);
        }
    }
#pragma unroll
    for (int s = 0; s < 2; ++s)
#pragma unroll
        for (int r = 0; r < 4; ++r)
            out[((size_t)b * NQ + q0 + s * 16 + quad * 4 + r) * 128 + hh * 16 + c] =
                oacc[s][r];
}

extern "C" void kernel_launch(void* const* d_in, const int* in_sizes, int n_in,
                              void* d_out, int out_size, void* d_ws, size_t ws_size,
                              hipStream_t stream) {
    const float* q    = (const float*)d_in[0];
    const float* h    = (const float*)d_in[1];
    const int*   mask = (const int*)d_in[2];
    const float* Wq   = (const float*)d_in[3];
    const float* Wk   = (const float*)d_in[4];
    const float* Wv   = (const float*)d_in[5];
    const float* Wout = (const float*)d_in[6];
    float* out = (float*)d_out;

    const size_t NTOK = (size_t)NB * NQ;     // 32768
    u16* Qb  = (u16*)d_ws;                   // 8 MB each
    u16* Kb  = Qb + NTOK * 128;
    u16* Vtg = Kb + NTOK * 128;              // V^T per batch, sigma-permuted slots
    u16* Wob = Vtg + NTOK * 128;             // prepped Wout, 32 KB

    proj_mfma<<<dim3(256, 4), 256, 0, stream>>>(q, h, Wq, Wk, Wv, Wout,
                                                Qb, Kb, Vtg, Wob);
    flash_mfma<<<dim3(NB, NQ / 32), 512, 0, stream>>>(Qb, Kb, Vtg, mask,
                                                      Wob, out);
}